// Round 1
// baseline (233.046 us; speedup 1.0000x reference)
//
#include <hip/hip_runtime.h>
#include <math.h>

// GaussianAdjacencyMatrix: out[b,i,j] = m*exp(-||x_i-x_j||^2/sigma^2) / (row_sum + 1e-8)
// B=8, N=2048, D=3. One 256-thread block per row; row kept in registers.

#define NN 2048
#define THREADS 256
#define EPS 1e-8f

__global__ __launch_bounds__(THREADS) void gauss_adj_kernel(
    const float* __restrict__ coords,   // [B, N, 3]
    const float* __restrict__ masks,    // [B, N, N]
    const float* __restrict__ sigma,    // [1]
    float* __restrict__ out)            // [B, N, N]
{
    const int row = blockIdx.x;         // b*N + i
    const int b   = row >> 11;          // / 2048
    const int i   = row & (NN - 1);
    const int tid = threadIdx.x;

    __shared__ __align__(16) float sx[NN];
    __shared__ __align__(16) float sy[NN];
    __shared__ __align__(16) float sz[NN];
    __shared__ float red[THREADS / 64];
    __shared__ float s_inv;

    // stage this batch's coordinates SoA into LDS (24 KiB; L2-served after first block)
    const float* cb = coords + (size_t)b * NN * 3;
    for (int idx = tid; idx < NN; idx += THREADS) {
        sx[idx] = cb[idx * 3 + 0];
        sy[idx] = cb[idx * 3 + 1];
        sz[idx] = cb[idx * 3 + 2];
    }
    __syncthreads();

    const float xi = sx[i];
    const float yi = sy[i];
    const float zi = sz[i];
    const float s  = sigma[0];
    const float inv_s2 = 1.0f / (s * s);

    const float4* mrow = (const float4*)(masks + (size_t)row * NN);
    float4*       orow = (float4*)(out + (size_t)row * NN);
    const float4* sx4 = (const float4*)sx;
    const float4* sy4 = (const float4*)sy;
    const float4* sz4 = (const float4*)sz;

    float vals[8];
    float lsum = 0.0f;

    #pragma unroll
    for (int c = 0; c < 2; ++c) {
        const int j4 = c * THREADS + tid;   // float4 index, 0..511
        const float4 m = mrow[j4];
        const float4 X = sx4[j4];
        const float4 Y = sy4[j4];
        const float4 Z = sz4[j4];
        const float mx[4] = {m.x, m.y, m.z, m.w};
        const float xs[4] = {X.x, X.y, X.z, X.w};
        const float ys[4] = {Y.x, Y.y, Y.z, Y.w};
        const float zs[4] = {Z.x, Z.y, Z.z, Z.w};
        #pragma unroll
        for (int k = 0; k < 4; ++k) {
            const float dx = xi - xs[k];
            const float dy = yi - ys[k];
            const float dz = zi - zs[k];
            const float d  = dx * dx + dy * dy + dz * dz;
            const float a  = __expf(-d * inv_s2) * mx[k];
            vals[c * 4 + k] = a;
            lsum += a;
        }
    }

    // wave64 butterfly reduce, then cross-wave via LDS
    #pragma unroll
    for (int off = 32; off > 0; off >>= 1)
        lsum += __shfl_down(lsum, off, 64);
    const int wave = tid >> 6;
    if ((tid & 63) == 0) red[wave] = lsum;
    __syncthreads();
    if (tid == 0) {
        float tot = red[0] + red[1] + red[2] + red[3];
        s_inv = 1.0f / (tot + EPS);
    }
    __syncthreads();
    const float inv = s_inv;

    #pragma unroll
    for (int c = 0; c < 2; ++c) {
        const int j4 = c * THREADS + tid;
        float4 o;
        o.x = vals[c * 4 + 0] * inv;
        o.y = vals[c * 4 + 1] * inv;
        o.z = vals[c * 4 + 2] * inv;
        o.w = vals[c * 4 + 3] * inv;
        orow[j4] = o;
    }
}

extern "C" void kernel_launch(void* const* d_in, const int* in_sizes, int n_in,
                              void* d_out, int out_size, void* d_ws, size_t ws_size,
                              hipStream_t stream) {
    const float* coords = (const float*)d_in[0];   // [B,N,3]
    const float* masks  = (const float*)d_in[1];   // [B,N,N]
    const float* sigma  = (const float*)d_in[2];   // [1]
    float* out = (float*)d_out;

    const int B = in_sizes[0] / (NN * 3);
    const int rows = B * NN;
    gauss_adj_kernel<<<rows, THREADS, 0, stream>>>(coords, masks, sigma, out);
}